// Round 7
// baseline (67.648 us; speedup 1.0000x reference)
//
#include <hip/hip_runtime.h>
#include <hip/hip_bf16.h>
#include <stdint.h>

typedef __attribute__((ext_vector_type(8)))  __bf16   bf16x8;
typedef __attribute__((ext_vector_type(16))) float    f32x16;
typedef __attribute__((ext_vector_type(2)))  float    f32x2;
typedef __attribute__((ext_vector_type(8)))  float    f32x8;

#define NB   32
#define NN   2000
#define NK   32
#define NF   64
#define NOUT 128
#define NSTEP 130   // packed K: 2048 x-part + 32 dist, /16

#define GLOBAL_AS __attribute__((address_space(1)))
#define LDS_AS    __attribute__((address_space(3)))
#define SB() __builtin_amdgcn_sched_barrier(0)

// ---------------------------------------------------------------------------
// Fused prep (verified R6). Blocks [0,NN): x -> xb2 frag-order tiles via LDS
// transpose + dist -> db bf16. Blocks [NN,NN+NSTEP): W -> Wf B-frag order.
// xb2 tile byte t*16 holds x[batch=col][f=s*16+half*8+j], t=s*64+half*32+col.
// Wf byte = kstep*4096 + wv*1024 + lane*16; o=wv*32+(lane&31), k=kstep*16+(lane>>5)*8+j.
// ---------------------------------------------------------------------------
__global__ void kprep(const float* __restrict__ x, const float* __restrict__ dist,
                      const float* __restrict__ W,
                      __bf16* __restrict__ xb2, __bf16* __restrict__ db,
                      __bf16* __restrict__ Wf) {
  const int t = threadIdx.x;
  if (blockIdx.x < NN) {
    __shared__ __bf16 sm[32 * 66];
    const int n = blockIdx.x;
    const int bb = t >> 3;
    const int f0 = (t & 7) << 3;
    const float* src = x + ((size_t)bb * NN + n) * NF + f0;
    f32x8 v = *(const f32x8*)src;
    bf16x8 r;
#pragma unroll
    for (int j = 0; j < 8; ++j) r[j] = (__bf16)v[j];
    *(bf16x8*)&sm[bb * 66 + f0] = r;
    __syncthreads();
    const int col = t & 31, half = (t >> 5) & 1, s = t >> 6;
    bf16x8 o = *(const bf16x8*)&sm[col * 66 + s * 16 + half * 8];
    *(bf16x8*)((char*)xb2 + ((size_t)n << 12) + t * 16) = o;
    if (t < NK) db[n * NK + t] = (__bf16)dist[n * NK + t];
  } else {
    const int kstep = blockIdx.x - NN;
    const int lane = t & 63;
    const int wv = t >> 6;
    const int o = wv * 32 + (lane & 31);
    const int kbase = kstep * 16 + (lane >> 5) * 8;
    bf16x8 r;
#pragma unroll
    for (int j = 0; j < 8; ++j) {
      const int kg = kbase + j;
      const int c = (kg < 2048) ? ((kg >> 6) * 65 + (kg & 63)) : ((kg - 2048) * 65 + 64);
      r[j] = (__bf16)W[(size_t)o * 2080 + c];
    }
    *(bf16x8*)(Wf + (((size_t)kstep * 256 + t) << 3)) = r;
  }
}

// ---------------------------------------------------------------------------
// Main: block = 2 n, 4 waves = (khalf = w>>1) x (ogp = w&1).
// Wave computes 2 og x 2 n over its K-half (chunks 2sc+kh), acc = 64 VGPR.
// 2 LDS slots x 16KB (4 tiles: [kh][np]); wave w stages tile w each superchunk.
// One barrier/superchunk; stage post-barrier; single-buffered B (8 frags).
// End: khalf partial sums reduced through LDS; kh=0 waves write out.
// ---------------------------------------------------------------------------
__global__ __launch_bounds__(256, 4) void kmain(
    const int* __restrict__ nbrs, const float* __restrict__ bias,
    const __bf16* __restrict__ xb2, const __bf16* __restrict__ Wf,
    const __bf16* __restrict__ db, float* __restrict__ out) {
  __shared__ __align__(16) char lds[2][4][4096];   // [slot][tile = kh*2+np][4KB]

  const int t    = threadIdx.x;
  const int lane = t & 63;
  const int w    = t >> 6;
  const int kh   = w >> 1;        // K-half: my chunks are 2*sc + kh
  const int ogp  = w & 1;         // out-group pair: og = 2*ogp + e
  const int col  = lane & 31;
  const int half = lane >> 5;
  const int n0   = blockIdx.x * 2;

  f32x16 acc00 = {}, acc01 = {}, acc10 = {}, acc11 = {};   // [np][e]

  // lane sc (<16) holds neighbor for superchunk sc of stream (n0+ogp, kh)
  int myidx = 0;
  if (lane < 16) myidx = nbrs[(n0 + ogp) * NK + lane * 2 + kh];

  // B-frag base: frag(chunk c, s, e) at wfb + (c*4+s)*4096 + e*1024
  const char* wfb = (const char*)Wf + (ogp << 11) + lane * 16;

  auto stage = [&](int slot, int sc) {     // wave w stages tile w (= kh*2+ogp)
    const int nb = __builtin_amdgcn_readlane(myidx, sc);
    const char* g = (const char*)xb2 + ((size_t)nb << 12) + lane * 16;
    char* l = &lds[slot][w][0];
#pragma unroll
    for (int q = 0; q < 4; ++q)
      __builtin_amdgcn_global_load_lds(
          (const GLOBAL_AS uint32_t*)(g + (q << 10)),
          (LDS_AS uint32_t*)(l + (q << 10)), 16, 0, 0);
  };

  bf16x8 B[8];
  auto loadB = [&](int sc) {               // 8 frags: 4 ksteps x 2 og
    const char* base = wfb + ((size_t)(sc * 2 + kh) << 14);
#pragma unroll
    for (int s = 0; s < 4; ++s) {
      B[s * 2 + 0] = *(const bf16x8*)(base + (s << 12));
      B[s * 2 + 1] = *(const bf16x8*)(base + (s << 12) + 1024);
    }
  };

  auto compute = [&](int slot) {
    __builtin_amdgcn_s_setprio(1);
#pragma unroll
    for (int s = 0; s < 4; ++s) {
      const char* lb = &lds[slot][kh << 1][0] + (s << 10) + lane * 16;
      bf16x8 a0 = *(const bf16x8*)(lb);            // np = 0
      bf16x8 a1 = *(const bf16x8*)(lb + 4096);     // np = 1
      acc00 = __builtin_amdgcn_mfma_f32_32x32x16_bf16(a0, B[s * 2 + 0], acc00, 0, 0, 0);
      acc01 = __builtin_amdgcn_mfma_f32_32x32x16_bf16(a0, B[s * 2 + 1], acc01, 0, 0, 0);
      acc10 = __builtin_amdgcn_mfma_f32_32x32x16_bf16(a1, B[s * 2 + 0], acc10, 0, 0, 0);
      acc11 = __builtin_amdgcn_mfma_f32_32x32x16_bf16(a1, B[s * 2 + 1], acc11, 0, 0, 0);
    }
    __builtin_amdgcn_s_setprio(0);
  };

  stage(0, 0);
  for (int sc = 0; sc < 16; ++sc) {
    const int slot = sc & 1;
    loadB(sc); SB();
    asm volatile("s_waitcnt vmcnt(0)" ::: "memory");   // own stage(sc)+loadB(sc) done
    __builtin_amdgcn_s_barrier(); SB();                // all tiles of sc visible
    if (sc < 15) { stage(slot ^ 1, sc + 1); SB(); }    // post-barrier: WAR-safe
    compute(slot);
  }

  // ---- distance kstep 128+kh (split across khalf waves; ogp splits og)
  {
    const char* wtail = wfb + ((size_t)(128 + kh) << 12);
    bf16x8 b0 = *(const bf16x8*)(wtail);
    bf16x8 b1 = *(const bf16x8*)(wtail + 1024);
    const char* dbase = (const char*)db + (size_t)n0 * 64 + kh * 32 + half * 16;
    bf16x8 d0 = *(const bf16x8*)(dbase);
    bf16x8 d1 = *(const bf16x8*)(dbase + 64);
    acc00 = __builtin_amdgcn_mfma_f32_32x32x16_bf16(d0, b0, acc00, 0, 0, 0);
    acc01 = __builtin_amdgcn_mfma_f32_32x32x16_bf16(d0, b1, acc01, 0, 0, 0);
    acc10 = __builtin_amdgcn_mfma_f32_32x32x16_bf16(d1, b0, acc10, 0, 0, 0);
    acc11 = __builtin_amdgcn_mfma_f32_32x32x16_bf16(d1, b1, acc11, 0, 0, 0);
  }

  // ---- khalf reduction through LDS: byte = ogp*16384 + p*512 + lane*8 (2-way free)
  __builtin_amdgcn_s_barrier();
  char* red = &lds[0][0][0];
  if (kh == 1) {
    char* pb = red + (ogp << 14) + lane * 8;
#pragma unroll
    for (int i = 0; i < 8; ++i) {
      f32x2 v;
      v[0] = acc00[2*i]; v[1] = acc00[2*i+1]; *(f32x2*)(pb + ((0*8+i) << 9)) = v;
      v[0] = acc01[2*i]; v[1] = acc01[2*i+1]; *(f32x2*)(pb + ((1*8+i) << 9)) = v;
      v[0] = acc10[2*i]; v[1] = acc10[2*i+1]; *(f32x2*)(pb + ((2*8+i) << 9)) = v;
      v[0] = acc11[2*i]; v[1] = acc11[2*i+1]; *(f32x2*)(pb + ((3*8+i) << 9)) = v;
    }
  }
  __builtin_amdgcn_s_barrier();
  if (kh == 0) {
    const char* pb = red + (ogp << 14) + lane * 8;
#pragma unroll
    for (int i = 0; i < 8; ++i) {
      f32x2 v;
      v = *(const f32x2*)(pb + ((0*8+i) << 9)); acc00[2*i] += v[0]; acc00[2*i+1] += v[1];
      v = *(const f32x2*)(pb + ((1*8+i) << 9)); acc01[2*i] += v[0]; acc01[2*i+1] += v[1];
      v = *(const f32x2*)(pb + ((2*8+i) << 9)); acc10[2*i] += v[0]; acc10[2*i+1] += v[1];
      v = *(const f32x2*)(pb + ((3*8+i) << 9)); acc11[2*i] += v[0]; acc11[2*i+1] += v[1];
    }
    const int o0 = (ogp << 6) + col;        // og = 2*ogp   -> out cols ogp*64 + col
    const float bv0 = bias[o0], bv1 = bias[o0 + 32];
#pragma unroll
    for (int r = 0; r < 16; ++r) {
      const int row = (r & 3) + 8 * (r >> 2) + 4 * half;
      float* op = out + ((size_t)row * NN + n0) * NOUT;
      op[o0]        = acc00[r] + bv0;
      op[o0 + 32]   = acc01[r] + bv1;
      op[NOUT + o0]      = acc10[r] + bv0;
      op[NOUT + o0 + 32] = acc11[r] + bv1;
    }
  }
}

// ---------------------------------------------------------------------------
extern "C" void kernel_launch(void* const* d_in, const int* in_sizes, int n_in,
                              void* d_out, int out_size, void* d_ws, size_t ws_size,
                              hipStream_t stream) {
  const float* x    = (const float*)d_in[0];
  const int*   nbrs = (const int*)d_in[1];
  const float* dist = (const float*)d_in[2];
  const float* W    = (const float*)d_in[3];
  const float* bias = (const float*)d_in[4];
  float* out = (float*)d_out;

  char* ws = (char*)d_ws;
  __bf16* xb2 = (__bf16*)(ws);                          // 2000*4096  = 8,192,000 B
  __bf16* Wf  = (__bf16*)(ws + 8192000);                // 130*256*16 =   532,480 B
  __bf16* db  = (__bf16*)(ws + 8192000 + 532480);       // 2000*32*2  =   128,000 B

  kprep<<<NN + NSTEP, 256, 0, stream>>>(x, dist, W, xb2, db, Wf);
  kmain<<<NN / 2, 256, 0, stream>>>(nbrs, bias, xb2, Wf, db, out);
}

// Round 8
// 60.498 us; speedup vs baseline: 1.1182x; 1.1182x over previous
//
#include <hip/hip_runtime.h>
#include <hip/hip_bf16.h>
#include <stdint.h>

typedef __attribute__((ext_vector_type(8)))  __bf16   bf16x8;
typedef __attribute__((ext_vector_type(16))) float    f32x16;
typedef __attribute__((ext_vector_type(8)))  float    f32x8;

#define NB   32
#define NN   2000
#define NK   32
#define NF   64
#define NOUT 128
#define NSTEP 130   // packed K: 2048 x-part + 32 dist, /16

#define GLOBAL_AS __attribute__((address_space(1)))
#define LDS_AS    __attribute__((address_space(3)))
#define SB() __builtin_amdgcn_sched_barrier(0)

// ---------------------------------------------------------------------------
// Fused prep (verified R6/R7). Blocks [0,NN): x -> xb2 frag-order tiles via
// LDS transpose + dist -> db bf16. Blocks [NN,NN+NSTEP): W -> Wf B-frag order.
// xb2 tile byte t*16 holds x[batch=col][f=s*16+half*8+j], t=s*64+half*32+col.
// Wf byte = kstep*4096 + wv*1024 + lane*16; o=wv*32+(lane&31), k=kstep*16+(lane>>5)*8+j.
// ---------------------------------------------------------------------------
__global__ void kprep(const float* __restrict__ x, const float* __restrict__ dist,
                      const float* __restrict__ W,
                      __bf16* __restrict__ xb2, __bf16* __restrict__ db,
                      __bf16* __restrict__ Wf) {
  const int t = threadIdx.x;
  if (blockIdx.x < NN) {
    __shared__ __bf16 sm[32 * 66];
    const int n = blockIdx.x;
    const int bb = t >> 3;
    const int f0 = (t & 7) << 3;
    const float* src = x + ((size_t)bb * NN + n) * NF + f0;
    f32x8 v = *(const f32x8*)src;
    bf16x8 r;
#pragma unroll
    for (int j = 0; j < 8; ++j) r[j] = (__bf16)v[j];
    *(bf16x8*)&sm[bb * 66 + f0] = r;
    __syncthreads();
    const int col = t & 31, half = (t >> 5) & 1, s = t >> 6;
    bf16x8 o = *(const bf16x8*)&sm[col * 66 + s * 16 + half * 8];
    *(bf16x8*)((char*)xb2 + ((size_t)n << 12) + t * 16) = o;
    if (t < NK) db[n * NK + t] = (__bf16)dist[n * NK + t];
  } else {
    const int kstep = blockIdx.x - NN;
    const int lane = t & 63;
    const int wv = t >> 6;
    const int o = wv * 32 + (lane & 31);
    const int kbase = kstep * 16 + (lane >> 5) * 8;
    bf16x8 r;
#pragma unroll
    for (int j = 0; j < 8; ++j) {
      const int kg = kbase + j;
      const int c = (kg < 2048) ? ((kg >> 6) * 65 + (kg & 63)) : ((kg - 2048) * 65 + 64);
      r[j] = (__bf16)W[(size_t)o * 2080 + c];
    }
    *(bf16x8*)(Wf + (((size_t)kstep * 256 + t) << 3)) = r;
  }
}

// ---------------------------------------------------------------------------
// Main: block = 128 threads = 2 waves, block covers 2 n x all 128 out.
// Wave = og-pair ogp: computes acc[2 n][2 og] (64 VGPR), stages tile n0+ogp.
// Depth-3 LDS (24KB), B double-buffered in regs, one 2-wave barrier/chunk,
// stage post-barrier (WAR-safe at depth 3), steady vmcnt(12):
//   queue at wait(c) = [S(c)4, L(c)8, S(c+1)4, L(c+1)8] -> retires S(c),L(c).
// ---------------------------------------------------------------------------
__global__ __launch_bounds__(128, 2) void kmain(
    const int* __restrict__ nbrs, const float* __restrict__ bias,
    const __bf16* __restrict__ xb2, const __bf16* __restrict__ Wf,
    const __bf16* __restrict__ db, float* __restrict__ out) {
  __shared__ __align__(16) char lds[3][2][4096];   // [buf][n'][frag-order tile]

  const int t    = threadIdx.x;
  const int lane = t & 63;
  const int ogp  = t >> 6;        // wave role: out-group pair (og = 2*ogp + e)
  const int col  = lane & 31;
  const int half = lane >> 5;
  const int n0   = blockIdx.x * 2;

  f32x16 acc00 = {}, acc01 = {}, acc10 = {}, acc11 = {};   // [n'][e]

  // wave ogp stages tile for n0+ogp; lane c holds its neighbor for chunk c
  int myidx = 0;
  if (lane < NK) myidx = nbrs[(n0 + ogp) * NK + lane];

  // B-frag byte for (kstep=c*4+s, og=2*ogp+e): (c*4+s)*4096 + (2*ogp+e)*1024
  const char* wfb = (const char*)Wf + (ogp << 11) + lane * 16;

  auto stage = [&](int buf, int c) {
    const int nb = __builtin_amdgcn_readlane(myidx, c);
    const char* g = (const char*)xb2 + ((size_t)nb << 12) + lane * 16;
    char* l = &lds[buf][ogp][0];
#pragma unroll
    for (int q = 0; q < 4; ++q)
      __builtin_amdgcn_global_load_lds(
          (const GLOBAL_AS uint32_t*)(g + (q << 10)),
          (LDS_AS uint32_t*)(l + (q << 10)), 16, 0, 0);
  };

  auto loadB = [&](bf16x8* B, int c) {   // 8 frags: 4 ksteps x 2 og
    const char* base = wfb + ((size_t)c << 14);
#pragma unroll
    for (int s = 0; s < 4; ++s) {
      B[s * 2 + 0] = *(const bf16x8*)(base + (s << 12));
      B[s * 2 + 1] = *(const bf16x8*)(base + (s << 12) + 1024);
    }
  };

  auto compute = [&](int buf, const bf16x8* B) {
    __builtin_amdgcn_s_setprio(1);
#pragma unroll
    for (int s = 0; s < 4; ++s) {
      const char* lb = &lds[buf][0][0] + (s << 10) + lane * 16;
      bf16x8 a0 = *(const bf16x8*)(lb);            // n' = 0
      bf16x8 a1 = *(const bf16x8*)(lb + 4096);     // n' = 1
      acc00 = __builtin_amdgcn_mfma_f32_32x32x16_bf16(a0, B[s * 2 + 0], acc00, 0, 0, 0);
      acc01 = __builtin_amdgcn_mfma_f32_32x32x16_bf16(a0, B[s * 2 + 1], acc01, 0, 0, 0);
      acc10 = __builtin_amdgcn_mfma_f32_32x32x16_bf16(a1, B[s * 2 + 0], acc10, 0, 0, 0);
      acc11 = __builtin_amdgcn_mfma_f32_32x32x16_bf16(a1, B[s * 2 + 1], acc11, 0, 0, 0);
    }
    __builtin_amdgcn_s_setprio(0);
  };

  bf16x8 BA[8], BB[8];

  // prologue: S(0), L(0), S(1) — matches steady queue shape
  stage(0, 0); SB();
  loadB(BA, 0); SB();
  stage(1, 1); SB();

#define HALF(C, CBUF, SBUF, BC, BL)                         \
  loadB(BL, (C) + 1); SB();                                 \
  asm volatile("s_waitcnt vmcnt(12)" ::: "memory");         \
  __builtin_amdgcn_s_barrier(); SB();                       \
  stage(SBUF, (C) + 2); SB();                               \
  compute(CBUF, BC);

  // chunks 0..29 in groups of 6 (buf cycle 0,1,2; bank cycle BA,BB)
  for (int base = 0; base < 30; base += 6) {
    HALF(base + 0, 0, 2, BA, BB)
    HALF(base + 1, 1, 0, BB, BA)
    HALF(base + 2, 2, 1, BA, BB)
    HALF(base + 3, 0, 2, BB, BA)
    HALF(base + 4, 1, 0, BA, BB)
    HALF(base + 5, 2, 1, BB, BA)
  }
#undef HALF
  // chunk 30: queue [S30,L30,S31,L31] -> vmcnt(12) retires S30,L30
  loadB(BB, 31); SB();
  asm volatile("s_waitcnt vmcnt(12)" ::: "memory");
  __builtin_amdgcn_s_barrier(); SB();
  compute(0, BA);
  // chunk 31
  asm volatile("s_waitcnt vmcnt(0)" ::: "memory");
  __builtin_amdgcn_s_barrier(); SB();
  compute(1, BB);

  // ---- distance ksteps 128,129 (A rows all equal d[n][k-slice])
#pragma unroll
  for (int s = 0; s < 2; ++s) {
    const char* wt = wfb + ((size_t)(128 + s) << 12);
    bf16x8 b0 = *(const bf16x8*)(wt);
    bf16x8 b1 = *(const bf16x8*)(wt + 1024);
    const char* dbase = (const char*)db + (size_t)n0 * 64 + s * 32 + half * 16;
    bf16x8 d0 = *(const bf16x8*)(dbase);        // n' = 0
    bf16x8 d1 = *(const bf16x8*)(dbase + 64);   // n' = 1
    acc00 = __builtin_amdgcn_mfma_f32_32x32x16_bf16(d0, b0, acc00, 0, 0, 0);
    acc01 = __builtin_amdgcn_mfma_f32_32x32x16_bf16(d0, b1, acc01, 0, 0, 0);
    acc10 = __builtin_amdgcn_mfma_f32_32x32x16_bf16(d1, b0, acc10, 0, 0, 0);
    acc11 = __builtin_amdgcn_mfma_f32_32x32x16_bf16(d1, b1, acc11, 0, 0, 0);
  }

  // ---- epilogue: D col=lane&31 -> out col, row=(r&3)+8*(r>>2)+4*half -> batch
  const int o0 = (ogp << 6) + col;
  const float bv0 = bias[o0], bv1 = bias[o0 + 32];
#pragma unroll
  for (int r = 0; r < 16; ++r) {
    const int row = (r & 3) + 8 * (r >> 2) + 4 * half;
    float* op = out + ((size_t)row * NN + n0) * NOUT + o0;
    op[0]         = acc00[r] + bv0;
    op[32]        = acc01[r] + bv1;
    op[NOUT]      = acc10[r] + bv0;
    op[NOUT + 32] = acc11[r] + bv1;
  }
}

// ---------------------------------------------------------------------------
extern "C" void kernel_launch(void* const* d_in, const int* in_sizes, int n_in,
                              void* d_out, int out_size, void* d_ws, size_t ws_size,
                              hipStream_t stream) {
  const float* x    = (const float*)d_in[0];
  const int*   nbrs = (const int*)d_in[1];
  const float* dist = (const float*)d_in[2];
  const float* W    = (const float*)d_in[3];
  const float* bias = (const float*)d_in[4];
  float* out = (float*)d_out;

  char* ws = (char*)d_ws;
  __bf16* xb2 = (__bf16*)(ws);                          // 2000*4096  = 8,192,000 B
  __bf16* Wf  = (__bf16*)(ws + 8192000);                // 130*256*16 =   532,480 B
  __bf16* db  = (__bf16*)(ws + 8192000 + 532480);       // 2000*32*2  =   128,000 B

  kprep<<<NN + NSTEP, 256, 0, stream>>>(x, dist, W, xb2, db, Wf);
  kmain<<<NN / 2, 128, 0, stream>>>(nbrs, bias, xb2, Wf, db, out);
}

// Round 9
// 58.799 us; speedup vs baseline: 1.1505x; 1.0289x over previous
//
#include <hip/hip_runtime.h>
#include <hip/hip_bf16.h>
#include <stdint.h>

typedef __attribute__((ext_vector_type(8)))  __bf16   bf16x8;
typedef __attribute__((ext_vector_type(16))) float    f32x16;
typedef __attribute__((ext_vector_type(2)))  float    f32x2;
typedef __attribute__((ext_vector_type(8)))  float    f32x8;

#define NB   32
#define NN   2000
#define NK   32
#define NF   64
#define NOUT 128
#define NSTEP 130   // packed K: 2048 x-part + 32 dist, /16

#define GLOBAL_AS __attribute__((address_space(1)))
#define LDS_AS    __attribute__((address_space(3)))
#define SB() __builtin_amdgcn_sched_barrier(0)

// ---------------------------------------------------------------------------
// Fused prep (verified R6-R8). Blocks [0,NN): x -> xb2 frag-order tiles via
// LDS transpose + dist -> db bf16. Blocks [NN,NN+NSTEP): W -> Wf B-frag order.
// xb2 tile byte t*16 holds x[batch=col][f=s*16+half*8+j], t=s*64+half*32+col.
// Wf byte = kstep*4096 + wv*1024 + lane*16; o=wv*32+(lane&31), k=kstep*16+(lane>>5)*8+j.
// ---------------------------------------------------------------------------
__global__ void kprep(const float* __restrict__ x, const float* __restrict__ dist,
                      const float* __restrict__ W,
                      __bf16* __restrict__ xb2, __bf16* __restrict__ db,
                      __bf16* __restrict__ Wf) {
  const int t = threadIdx.x;
  if (blockIdx.x < NN) {
    __shared__ __bf16 sm[32 * 66];
    const int n = blockIdx.x;
    const int bb = t >> 3;
    const int f0 = (t & 7) << 3;
    const float* src = x + ((size_t)bb * NN + n) * NF + f0;
    f32x8 v = *(const f32x8*)src;
    bf16x8 r;
#pragma unroll
    for (int j = 0; j < 8; ++j) r[j] = (__bf16)v[j];
    *(bf16x8*)&sm[bb * 66 + f0] = r;
    __syncthreads();
    const int col = t & 31, half = (t >> 5) & 1, s = t >> 6;
    bf16x8 o = *(const bf16x8*)&sm[col * 66 + s * 16 + half * 8];
    *(bf16x8*)((char*)xb2 + ((size_t)n << 12) + t * 16) = o;
    if (t < NK) db[n * NK + t] = (__bf16)dist[n * NK + t];
  } else {
    const int kstep = blockIdx.x - NN;
    const int lane = t & 63;
    const int wv = t >> 6;
    const int o = wv * 32 + (lane & 31);
    const int kbase = kstep * 16 + (lane >> 5) * 8;
    bf16x8 r;
#pragma unroll
    for (int j = 0; j < 8; ++j) {
      const int kg = kbase + j;
      const int c = (kg < 2048) ? ((kg >> 6) * 65 + (kg & 63)) : ((kg - 2048) * 65 + 64);
      r[j] = (__bf16)W[(size_t)o * 2080 + c];
    }
    *(bf16x8*)(Wf + (((size_t)kstep * 256 + t) << 3)) = r;
  }
}

// ---------------------------------------------------------------------------
// Main: block = 2 n, 4 waves = (kh = w>>1) x (ogp = w&1). Stream kh processes
// global chunks 2*sc+kh, sc=0..15. Wave: acc[2 n][2 og] (64 VGPR), stages
// tile (kh, np=ogp). Depth-3 LDS per slot pair (48KB), B reg ping-pong,
// stage post-barrier, steady vmcnt(12): queue [S(sc),L(sc),S(sc+1),L(sc+1)].
// End: kh partials reduced through LDS (R7-verified); kh=0 writes out.
// ---------------------------------------------------------------------------
__global__ __launch_bounds__(256, 3) void kmain(
    const int* __restrict__ nbrs, const float* __restrict__ bias,
    const __bf16* __restrict__ xb2, const __bf16* __restrict__ Wf,
    const __bf16* __restrict__ db, float* __restrict__ out) {
  __shared__ __align__(16) char lds[3][2][2][4096];   // [buf][kh][np][tile]

  const int t    = threadIdx.x;
  const int lane = t & 63;
  const int w    = t >> 6;
  const int kh   = w >> 1;
  const int ogp  = w & 1;
  const int col  = lane & 31;
  const int half = lane >> 5;
  const int n0   = blockIdx.x * 2;

  f32x16 acc00 = {}, acc01 = {}, acc10 = {}, acc11 = {};   // [np][e]

  // lane sc (<16) holds neighbor for superchunk sc of stream (n0+ogp, kh)
  int myidx = 0;
  if (lane < 16) myidx = nbrs[(n0 + ogp) * NK + lane * 2 + kh];

  // B-frag byte for (kstep, og=2*ogp+e): kstep*4096 + (2*ogp+e)*1024 + lane*16
  const char* wfb = (const char*)Wf + (ogp << 11) + lane * 16;

  auto stage = [&](int buf, int sc) {      // wave stages tile (kh, np=ogp)
    const int nb = __builtin_amdgcn_readlane(myidx, sc);
    const char* g = (const char*)xb2 + ((size_t)nb << 12) + lane * 16;
    char* l = &lds[buf][kh][ogp][0];
#pragma unroll
    for (int q = 0; q < 4; ++q)
      __builtin_amdgcn_global_load_lds(
          (const GLOBAL_AS uint32_t*)(g + (q << 10)),
          (LDS_AS uint32_t*)(l + (q << 10)), 16, 0, 0);
  };

  auto loadB = [&](bf16x8* B, int sc) {    // 8 frags: 4 ksteps x 2 og
    const char* base = wfb + ((size_t)(sc * 2 + kh) << 14);
#pragma unroll
    for (int s = 0; s < 4; ++s) {
      B[s * 2 + 0] = *(const bf16x8*)(base + (s << 12));
      B[s * 2 + 1] = *(const bf16x8*)(base + (s << 12) + 1024);
    }
  };

  auto compute = [&](int buf, const bf16x8* B) {
    __builtin_amdgcn_s_setprio(1);
#pragma unroll
    for (int s = 0; s < 4; ++s) {
      const char* lb = &lds[buf][kh][0][0] + (s << 10) + lane * 16;
      bf16x8 a0 = *(const bf16x8*)(lb);            // np = 0
      bf16x8 a1 = *(const bf16x8*)(lb + 4096);     // np = 1
      acc00 = __builtin_amdgcn_mfma_f32_32x32x16_bf16(a0, B[s * 2 + 0], acc00, 0, 0, 0);
      acc01 = __builtin_amdgcn_mfma_f32_32x32x16_bf16(a0, B[s * 2 + 1], acc01, 0, 0, 0);
      acc10 = __builtin_amdgcn_mfma_f32_32x32x16_bf16(a1, B[s * 2 + 0], acc10, 0, 0, 0);
      acc11 = __builtin_amdgcn_mfma_f32_32x32x16_bf16(a1, B[s * 2 + 1], acc11, 0, 0, 0);
    }
    __builtin_amdgcn_s_setprio(0);
  };

  bf16x8 BA[8], BB[8];

  // prologue: S(0), L(0), S(1) — queue order matches steady shape
  stage(0, 0); SB();
  loadB(BA, 0); SB();
  stage(1, 1); SB();

#define HALF(C, CBUF, SBUF, BC, BL)                         \
  loadB(BL, (C) + 1); SB();                                 \
  asm volatile("s_waitcnt vmcnt(12)" ::: "memory");         \
  __builtin_amdgcn_s_barrier(); SB();                       \
  stage(SBUF, (C) + 2); SB();                               \
  compute(CBUF, BC);

  // superchunks 0..11 (buf cycle 0,1,2; bank cycle BA,BB; period 6)
  for (int base = 0; base < 12; base += 6) {
    HALF(base + 0, 0, 2, BA, BB)
    HALF(base + 1, 1, 0, BB, BA)
    HALF(base + 2, 2, 1, BA, BB)
    HALF(base + 3, 0, 2, BB, BA)
    HALF(base + 4, 1, 0, BA, BB)
    HALF(base + 5, 2, 1, BB, BA)
  }
  HALF(12, 0, 2, BA, BB)
  HALF(13, 1, 0, BB, BA)
#undef HALF
  // sc=14: queue [S14,L14,S15,L15] -> vmcnt(12) retires S14,L14
  loadB(BB, 15); SB();
  asm volatile("s_waitcnt vmcnt(12)" ::: "memory");
  __builtin_amdgcn_s_barrier(); SB();
  compute(2, BA);
  // sc=15
  asm volatile("s_waitcnt vmcnt(0)" ::: "memory");
  __builtin_amdgcn_s_barrier(); SB();
  compute(0, BB);

  // ---- distance kstep 128+kh (kh splits the two tail ksteps)
  {
    const char* wt = wfb + ((size_t)(128 + kh) << 12);
    bf16x8 b0 = *(const bf16x8*)(wt);
    bf16x8 b1 = *(const bf16x8*)(wt + 1024);
    const char* dbase = (const char*)db + (size_t)n0 * 64 + kh * 32 + half * 16;
    bf16x8 d0 = *(const bf16x8*)(dbase);        // n' = 0
    bf16x8 d1 = *(const bf16x8*)(dbase + 64);   // n' = 1
    acc00 = __builtin_amdgcn_mfma_f32_32x32x16_bf16(d0, b0, acc00, 0, 0, 0);
    acc01 = __builtin_amdgcn_mfma_f32_32x32x16_bf16(d0, b1, acc01, 0, 0, 0);
    acc10 = __builtin_amdgcn_mfma_f32_32x32x16_bf16(d1, b0, acc10, 0, 0, 0);
    acc11 = __builtin_amdgcn_mfma_f32_32x32x16_bf16(d1, b1, acc11, 0, 0, 0);
  }

  // ---- kh reduction through LDS (R7-verified layout: 2-way bank-free)
  __builtin_amdgcn_s_barrier();
  char* red = &lds[0][0][0][0];
  if (kh == 1) {
    char* pb = red + (ogp << 14) + lane * 8;
#pragma unroll
    for (int i = 0; i < 8; ++i) {
      f32x2 v;
      v[0] = acc00[2*i]; v[1] = acc00[2*i+1]; *(f32x2*)(pb + ((0*8+i) << 9)) = v;
      v[0] = acc01[2*i]; v[1] = acc01[2*i+1]; *(f32x2*)(pb + ((1*8+i) << 9)) = v;
      v[0] = acc10[2*i]; v[1] = acc10[2*i+1]; *(f32x2*)(pb + ((2*8+i) << 9)) = v;
      v[0] = acc11[2*i]; v[1] = acc11[2*i+1]; *(f32x2*)(pb + ((3*8+i) << 9)) = v;
    }
  }
  __builtin_amdgcn_s_barrier();
  if (kh == 0) {
    const char* pb = red + (ogp << 14) + lane * 8;
#pragma unroll
    for (int i = 0; i < 8; ++i) {
      f32x2 v;
      v = *(const f32x2*)(pb + ((0*8+i) << 9)); acc00[2*i] += v[0]; acc00[2*i+1] += v[1];
      v = *(const f32x2*)(pb + ((1*8+i) << 9)); acc01[2*i] += v[0]; acc01[2*i+1] += v[1];
      v = *(const f32x2*)(pb + ((2*8+i) << 9)); acc10[2*i] += v[0]; acc10[2*i+1] += v[1];
      v = *(const f32x2*)(pb + ((3*8+i) << 9)); acc11[2*i] += v[0]; acc11[2*i+1] += v[1];
    }
    const int o0 = (ogp << 6) + col;
    const float bv0 = bias[o0], bv1 = bias[o0 + 32];
#pragma unroll
    for (int r = 0; r < 16; ++r) {
      const int row = (r & 3) + 8 * (r >> 2) + 4 * half;
      float* op = out + ((size_t)row * NN + n0) * NOUT;
      op[o0]             = acc00[r] + bv0;
      op[o0 + 32]        = acc01[r] + bv1;
      op[NOUT + o0]      = acc10[r] + bv0;
      op[NOUT + o0 + 32] = acc11[r] + bv1;
    }
  }
}

// ---------------------------------------------------------------------------
extern "C" void kernel_launch(void* const* d_in, const int* in_sizes, int n_in,
                              void* d_out, int out_size, void* d_ws, size_t ws_size,
                              hipStream_t stream) {
  const float* x    = (const float*)d_in[0];
  const int*   nbrs = (const int*)d_in[1];
  const float* dist = (const float*)d_in[2];
  const float* W    = (const float*)d_in[3];
  const float* bias = (const float*)d_in[4];
  float* out = (float*)d_out;

  char* ws = (char*)d_ws;
  __bf16* xb2 = (__bf16*)(ws);                          // 2000*4096  = 8,192,000 B
  __bf16* Wf  = (__bf16*)(ws + 8192000);                // 130*256*16 =   532,480 B
  __bf16* db  = (__bf16*)(ws + 8192000 + 532480);       // 2000*32*2  =   128,000 B

  kprep<<<NN + NSTEP, 256, 0, stream>>>(x, dist, W, xb2, db, Wf);
  kmain<<<NN / 2, 256, 0, stream>>>(nbrs, bias, xb2, Wf, db, out);
}